// Round 7
// baseline (379.288 us; speedup 1.0000x reference)
//
#include <hip/hip_runtime.h>
#include <math.h>

#define NN 100000
#define NE 1600000
#define EPSBN 1e-5f
#define NBUCK 391   // ceil(NN/256); bucket = dst>>8

// ---------------- bf16 helpers ----------------
static __device__ __forceinline__ unsigned short f2bf(float f) {
    unsigned int u = __float_as_uint(f);
    u += 0x7fffu + ((u >> 16) & 1u);   // round-to-nearest-even
    return (unsigned short)(u >> 16);
}
static __device__ __forceinline__ float bf2f(unsigned short s) {
    return __uint_as_float(((unsigned int)s) << 16);
}
static __device__ __forceinline__ float4 bf4_to_f4(ushort4 u) {
    float4 c; c.x = bf2f(u.x); c.y = bf2f(u.y); c.z = bf2f(u.z); c.w = bf2f(u.w);
    return c;
}
static __device__ __forceinline__ void add4(float4& a, float4 c) {
    a.x += c.x; a.y += c.y; a.z += c.z; a.w += c.w;
}
static __device__ __forceinline__ void fma4(float4& a, float s, const float4& w) {
    a.x = fmaf(s, w.x, a.x); a.y = fmaf(s, w.y, a.y);
    a.z = fmaf(s, w.z, a.z); a.w = fmaf(s, w.w, a.w);
}
static __device__ __forceinline__ void fma2(float2& a, float s, const float2& w) {
    a.x = fmaf(s, w.x, a.x); a.y = fmaf(s, w.y, a.y);
}

// ---------------- CSR build ----------------
__global__ __launch_bounds__(512) void init_small(int* __restrict__ bkcnt,
                                                  int* __restrict__ bcur) {
    int t = threadIdx.x;
    bkcnt[t] = 0;
    bcur[t] = 0;
}

__global__ __launch_bounds__(256) void bucket_count(const int* __restrict__ dst,
                                                    int* __restrict__ bkcnt) {
    __shared__ int lh[NBUCK];
    int t = threadIdx.x;
    for (int b = t; b < NBUCK; b += 256) lh[b] = 0;
    __syncthreads();
    int e0 = blockIdx.x * 4096;
#pragma unroll
    for (int i = 0; i < 16; ++i) {
        int e = e0 + i * 256 + t;
        if (e < NE) atomicAdd(&lh[dst[e] >> 8], 1);
    }
    __syncthreads();
    for (int b = t; b < NBUCK; b += 256)
        if (lh[b]) atomicAdd(&bkcnt[b], lh[b]);
}

__global__ __launch_bounds__(512) void scan2(const int* __restrict__ bkcnt,
                                             int* __restrict__ bb0) {
    __shared__ int sh[512];
    int t = threadIdx.x;
    int val = (t < NBUCK) ? bkcnt[t] : 0;
    sh[t] = val;
    __syncthreads();
    for (int off = 1; off < 512; off <<= 1) {
        int x = (t >= off) ? sh[t - off] : 0;
        __syncthreads();
        sh[t] += x;
        __syncthreads();
    }
    bb0[t] = sh[t] - val;  // exclusive; bb0[NBUCK] == NE
}

__global__ __launch_bounds__(256) void bin_kernel(const int* __restrict__ src,
                                                  const int* __restrict__ dst,
                                                  const int* __restrict__ bb0,
                                                  int* __restrict__ bcur,
                                                  unsigned int* __restrict__ bucketed) {
    __shared__ int lh[NBUCK];
    __shared__ int lbase[NBUCK];
    __shared__ int lcur[NBUCK];
    int t = threadIdx.x;
    for (int b = t; b < NBUCK; b += 256) lh[b] = 0;
    __syncthreads();
    int e0 = blockIdx.x * 4096;
#pragma unroll
    for (int i = 0; i < 16; ++i) {
        int e = e0 + i * 256 + t;
        if (e < NE) atomicAdd(&lh[dst[e] >> 8], 1);
    }
    __syncthreads();
    for (int b = t; b < NBUCK; b += 256) {
        lbase[b] = bb0[b] + atomicAdd(&bcur[b], lh[b]);
        lcur[b] = 0;
    }
    __syncthreads();
#pragma unroll
    for (int i = 0; i < 16; ++i) {
        int e = e0 + i * 256 + t;
        if (e < NE) {
            int d = dst[e], s = src[e];
            int b = d >> 8;
            int pos = lbase[b] + atomicAdd(&lcur[b], 1);
            bucketed[pos] = (unsigned int)s | ((unsigned int)(d & 255) << 24);
        }
    }
}

__global__ __launch_bounds__(256) void fine_scatter_fused(const unsigned int* __restrict__ bucketed,
                                                          const int* __restrict__ bb0,
                                                          int* __restrict__ row_start,
                                                          float* __restrict__ dinv,
                                                          int* __restrict__ sorted_src) {
    __shared__ int hist[256];
    __shared__ int sc[256];
    __shared__ int rsl[256];
    __shared__ int lcur[256];
    int b = blockIdx.x, t = threadIdx.x;
    hist[t] = 0; lcur[t] = 0;
    __syncthreads();
    int e0 = bb0[b], e1 = bb0[b + 1];
    for (int e = e0 + t; e < e1; e += 256)
        atomicAdd(&hist[bucketed[e] >> 24], 1);
    __syncthreads();
    int val = hist[t];
    sc[t] = val;
    __syncthreads();
    for (int off = 1; off < 256; off <<= 1) {
        int x = (t >= off) ? sc[t - off] : 0;
        __syncthreads();
        sc[t] += x;
        __syncthreads();
    }
    int ex = sc[t] - val;
    int node = b * 256 + t;
    if (node < NN) {
        row_start[node] = e0 + ex;
        dinv[node] = rsqrtf(1.0f + (float)val);
    }
    if (node == NN) row_start[NN] = NE;
    rsl[t] = e0 + ex;
    __syncthreads();
    for (int e = e0 + t; e < e1; e += 256) {
        unsigned int p = bucketed[e];
        int dl = (int)(p >> 24);
        int pos = rsl[dl] + atomicAdd(&lcur[dl], 1);
        sorted_src[pos] = (int)(p & 0xFFFFFFu);
    }
}

// ---------------- GEMMs: reg-blocked 4x4, W staged in LDS, unroll capped ------
__global__ __launch_bounds__(256) void gemm_128_64_v3(const float* __restrict__ x,
                                                      const float* __restrict__ W,
                                                      const float* __restrict__ dinv,
                                                      unsigned short* __restrict__ hs) {
    __shared__ float xs[64][132];
    __shared__ float ws[128][64];
    int tid = threadIdx.x;
    int bn = blockIdx.x * 64;
    for (int id = tid; id < 2048; id += 256) {
        int r = id >> 4, c4 = id & 15;
        *(float4*)&ws[r][c4 * 4] = *(const float4*)(W + r * 64 + c4 * 4);
    }
    for (int id = tid; id < 64 * 33; id += 256) {
        int r = id / 33, c4 = id - r * 33;
        int n = bn + r; if (n >= NN) n = NN - 1;
        float4 v = make_float4(0.f, 0.f, 0.f, 0.f);
        if (c4 < 32) v = *(const float4*)(x + (size_t)n * 128 + c4 * 4);
        *(float4*)&xs[r][c4 * 4] = v;
    }
    __syncthreads();
    int tn = tid >> 4, tf = tid & 15;
    int f0 = tf * 4;
    float4 acc[4] = {{0,0,0,0},{0,0,0,0},{0,0,0,0},{0,0,0,0}};
#pragma unroll 2
    for (int k = 0; k < 128; k += 4) {
        float4 w0 = *(const float4*)&ws[k + 0][f0];
        float4 w1 = *(const float4*)&ws[k + 1][f0];
        float4 w2 = *(const float4*)&ws[k + 2][f0];
        float4 w3 = *(const float4*)&ws[k + 3][f0];
#pragma unroll
        for (int i = 0; i < 4; ++i) {
            float4 xa = *(const float4*)&xs[tn * 4 + i][k];
            fma4(acc[i], xa.x, w0); fma4(acc[i], xa.y, w1);
            fma4(acc[i], xa.z, w2); fma4(acc[i], xa.w, w3);
        }
    }
#pragma unroll
    for (int i = 0; i < 4; ++i) {
        int n = bn + tn * 4 + i;
        if (n < NN) {
            float di = dinv[n];
            ushort4 u;
            u.x = f2bf(acc[i].x * di); u.y = f2bf(acc[i].y * di);
            u.z = f2bf(acc[i].z * di); u.w = f2bf(acc[i].w * di);
            *(ushort4*)(hs + (size_t)n * 64 + f0) = u;
        }
    }
}

__global__ __launch_bounds__(256) void gemm_64_64_v3(const float* __restrict__ x,
                                                     const float* __restrict__ W,
                                                     const float* __restrict__ dinv,
                                                     unsigned short* __restrict__ hs) {
    __shared__ float xs[64][68];
    __shared__ float ws[64][64];
    int tid = threadIdx.x;
    int bn = blockIdx.x * 64;
    for (int id = tid; id < 1024; id += 256) {
        int r = id >> 4, c4 = id & 15;
        *(float4*)&ws[r][c4 * 4] = *(const float4*)(W + r * 64 + c4 * 4);
    }
    for (int id = tid; id < 64 * 17; id += 256) {
        int r = id / 17, c4 = id - r * 17;
        int n = bn + r; if (n >= NN) n = NN - 1;
        float4 v = make_float4(0.f, 0.f, 0.f, 0.f);
        if (c4 < 16) v = *(const float4*)(x + (size_t)n * 64 + c4 * 4);
        *(float4*)&xs[r][c4 * 4] = v;
    }
    __syncthreads();
    int tn = tid >> 4, tf = tid & 15;
    int f0 = tf * 4;
    float4 acc[4] = {{0,0,0,0},{0,0,0,0},{0,0,0,0},{0,0,0,0}};
#pragma unroll 2
    for (int k = 0; k < 64; k += 4) {
        float4 w0 = *(const float4*)&ws[k + 0][f0];
        float4 w1 = *(const float4*)&ws[k + 1][f0];
        float4 w2 = *(const float4*)&ws[k + 2][f0];
        float4 w3 = *(const float4*)&ws[k + 3][f0];
#pragma unroll
        for (int i = 0; i < 4; ++i) {
            float4 xa = *(const float4*)&xs[tn * 4 + i][k];
            fma4(acc[i], xa.x, w0); fma4(acc[i], xa.y, w1);
            fma4(acc[i], xa.z, w2); fma4(acc[i], xa.w, w3);
        }
    }
#pragma unroll
    for (int i = 0; i < 4; ++i) {
        int n = bn + tn * 4 + i;
        if (n < NN) {
            float di = dinv[n];
            ushort4 u;
            u.x = f2bf(acc[i].x * di); u.y = f2bf(acc[i].y * di);
            u.z = f2bf(acc[i].z * di); u.w = f2bf(acc[i].w * di);
            *(ushort4*)(hs + (size_t)n * 64 + f0) = u;
        }
    }
}

__global__ __launch_bounds__(256) void gemm_64_16_v3(const float* __restrict__ x,
                                                     const float* __restrict__ W,
                                                     const float* __restrict__ dinv,
                                                     unsigned short* __restrict__ hs) {
    __shared__ float xs[128][68];
    __shared__ float ws[64][16];
    int tid = threadIdx.x;
    int bn = blockIdx.x * 128;
    for (int id = tid; id < 256; id += 256) {
        int r = id >> 2, c4 = id & 3;
        *(float4*)&ws[r][c4 * 4] = *(const float4*)(W + r * 16 + c4 * 4);
    }
    for (int id = tid; id < 128 * 17; id += 256) {
        int r = id / 17, c4 = id - r * 17;
        int n = bn + r; if (n >= NN) n = NN - 1;
        float4 v = make_float4(0.f, 0.f, 0.f, 0.f);
        if (c4 < 16) v = *(const float4*)(x + (size_t)n * 64 + c4 * 4);
        *(float4*)&xs[r][c4 * 4] = v;
    }
    __syncthreads();
    int tn = tid >> 3, tf = tid & 7;
    int f0 = tf * 2;
    float2 acc[4] = {{0,0},{0,0},{0,0},{0,0}};
#pragma unroll 2
    for (int k = 0; k < 64; k += 4) {
        float2 w0 = *(const float2*)&ws[k + 0][f0];
        float2 w1 = *(const float2*)&ws[k + 1][f0];
        float2 w2 = *(const float2*)&ws[k + 2][f0];
        float2 w3 = *(const float2*)&ws[k + 3][f0];
#pragma unroll
        for (int i = 0; i < 4; ++i) {
            float4 xa = *(const float4*)&xs[tn * 4 + i][k];
            fma2(acc[i], xa.x, w0); fma2(acc[i], xa.y, w1);
            fma2(acc[i], xa.z, w2); fma2(acc[i], xa.w, w3);
        }
    }
#pragma unroll
    for (int i = 0; i < 4; ++i) {
        int n = bn + tn * 4 + i;
        if (n < NN) {
            float di = dinv[n];
            ushort2 u;
            u.x = f2bf(acc[i].x * di); u.y = f2bf(acc[i].y * di);
            *(ushort2*)(hs + (size_t)n * 16 + f0) = u;
        }
    }
}

// ---------------- CSR aggregation v2: 16-lane groups, 4 edges/gather-instr ----
// wave = 1 dst row; group g (of 4) handles edges jj+g; lane loads ushort4 (4 feats)
__global__ __launch_bounds__(256) void csr_agg64_v2(const int* __restrict__ rs,
                                                    const int* __restrict__ ss,
                                                    const unsigned short* __restrict__ hs,
                                                    const float* __restrict__ dinv,
                                                    const float* __restrict__ b,
                                                    const float* __restrict__ g,
                                                    const float* __restrict__ be,
                                                    const float* __restrict__ m,
                                                    const float* __restrict__ v,
                                                    float* __restrict__ out) {
    int lane = threadIdx.x & 63;
    int r = blockIdx.x * 4 + (threadIdx.x >> 6);
    int grp = lane >> 4, fl = lane & 15;
    int e0 = rs[r], e1 = rs[r + 1];
    float4 a0 = {0,0,0,0}, a1 = {0,0,0,0}, a2 = {0,0,0,0}, a3 = {0,0,0,0};
    if (grp == 0)   // self loop
        a0 = bf4_to_f4(*(const ushort4*)(hs + (size_t)r * 64 + fl * 4));
    int jj = e0;
    for (; jj + 16 <= e1; jj += 16) {
        int s0 = ss[jj + grp];
        int s1 = ss[jj + 4 + grp];
        int s2 = ss[jj + 8 + grp];
        int s3 = ss[jj + 12 + grp];
        ushort4 u0 = *(const ushort4*)(hs + (size_t)s0 * 64 + fl * 4);
        ushort4 u1 = *(const ushort4*)(hs + (size_t)s1 * 64 + fl * 4);
        ushort4 u2 = *(const ushort4*)(hs + (size_t)s2 * 64 + fl * 4);
        ushort4 u3 = *(const ushort4*)(hs + (size_t)s3 * 64 + fl * 4);
        add4(a0, bf4_to_f4(u0)); add4(a1, bf4_to_f4(u1));
        add4(a2, bf4_to_f4(u2)); add4(a3, bf4_to_f4(u3));
    }
    for (; jj < e1; jj += 4) {
        int idx = jj + grp;
        if (idx < e1) {
            int s = ss[idx];
            add4(a1, bf4_to_f4(*(const ushort4*)(hs + (size_t)s * 64 + fl * 4)));
        }
    }
    add4(a0, a1); add4(a2, a3); add4(a0, a2);
    // cross-group reduce (4 groups -> lanes 0-15 hold full sums)
    a0.x += __shfl_xor(a0.x, 16); a0.y += __shfl_xor(a0.y, 16);
    a0.z += __shfl_xor(a0.z, 16); a0.w += __shfl_xor(a0.w, 16);
    a0.x += __shfl_xor(a0.x, 32); a0.y += __shfl_xor(a0.y, 32);
    a0.z += __shfl_xor(a0.z, 32); a0.w += __shfl_xor(a0.w, 32);
    if (grp == 0) {
        float di = dinv[r];
        float4 bb = *(const float4*)(b + fl * 4);
        float4 gg = *(const float4*)(g + fl * 4);
        float4 bz = *(const float4*)(be + fl * 4);
        float4 mm = *(const float4*)(m + fl * 4);
        float4 vv = *(const float4*)(v + fl * 4);
        float4 h;
        h.x = fmaxf(gg.x * (di * a0.x + bb.x - mm.x) * rsqrtf(vv.x + EPSBN) + bz.x, 0.f);
        h.y = fmaxf(gg.y * (di * a0.y + bb.y - mm.y) * rsqrtf(vv.y + EPSBN) + bz.y, 0.f);
        h.z = fmaxf(gg.z * (di * a0.z + bb.z - mm.z) * rsqrtf(vv.z + EPSBN) + bz.z, 0.f);
        h.w = fmaxf(gg.w * (di * a0.w + bb.w - mm.w) * rsqrtf(vv.w + EPSBN) + bz.w, 0.f);
        *(float4*)(out + (size_t)r * 64 + fl * 4) = h;
    }
}

// wave = 1 dst row; 8 groups of 8 lanes; lane loads ushort2 (2 feats); 8 edges/instr
__global__ __launch_bounds__(256) void csr_agg16_v2(const int* __restrict__ rs,
                                                    const int* __restrict__ ss,
                                                    const unsigned short* __restrict__ hs,
                                                    const float* __restrict__ dinv,
                                                    const float* __restrict__ b,
                                                    float* __restrict__ out) {
    int lane = threadIdx.x & 63;
    int r = blockIdx.x * 4 + (threadIdx.x >> 6);
    int grp = lane >> 3, fl = lane & 7;
    int e0 = rs[r], e1 = rs[r + 1];
    float2 a0 = {0,0}, a1 = {0,0};
    if (grp == 0) {
        ushort2 u = *(const ushort2*)(hs + (size_t)r * 16 + fl * 2);
        a0.x = bf2f(u.x); a0.y = bf2f(u.y);
    }
    int jj = e0;
    for (; jj + 16 <= e1; jj += 16) {
        int s0 = ss[jj + grp];
        int s1 = ss[jj + 8 + grp];
        ushort2 u0 = *(const ushort2*)(hs + (size_t)s0 * 16 + fl * 2);
        ushort2 u1 = *(const ushort2*)(hs + (size_t)s1 * 16 + fl * 2);
        a0.x += bf2f(u0.x); a0.y += bf2f(u0.y);
        a1.x += bf2f(u1.x); a1.y += bf2f(u1.y);
    }
    for (; jj < e1; jj += 8) {
        int idx = jj + grp;
        if (idx < e1) {
            int s = ss[idx];
            ushort2 u = *(const ushort2*)(hs + (size_t)s * 16 + fl * 2);
            a1.x += bf2f(u.x); a1.y += bf2f(u.y);
        }
    }
    a0.x += a1.x; a0.y += a1.y;
    a0.x += __shfl_xor(a0.x, 8);  a0.y += __shfl_xor(a0.y, 8);
    a0.x += __shfl_xor(a0.x, 16); a0.y += __shfl_xor(a0.y, 16);
    a0.x += __shfl_xor(a0.x, 32); a0.y += __shfl_xor(a0.y, 32);
    if (grp == 0) {
        float di = dinv[r];
        float hx = di * a0.x + b[fl * 2];
        float hy = di * a0.y + b[fl * 2 + 1];
        float2 o;
        o.x = 1.0f / (1.0f + expf(-hx));
        o.y = 1.0f / (1.0f + expf(-hy));
        *(float2*)(out + (size_t)r * 16 + fl * 2) = o;
    }
}

extern "C" void kernel_launch(void* const* d_in, const int* in_sizes, int n_in,
                              void* d_out, int out_size, void* d_ws, size_t ws_size,
                              hipStream_t stream) {
    const float* x   = (const float*)d_in[0];
    const int*   ei  = (const int*)d_in[1];   // [2, E]: src = ei, dst = ei + NE
    const float* W1  = (const float*)d_in[2];
    const float* b1  = (const float*)d_in[3];
    const float* W2  = (const float*)d_in[4];
    const float* b2  = (const float*)d_in[5];
    const float* W3  = (const float*)d_in[6];
    const float* b3  = (const float*)d_in[7];
    const float* g1  = (const float*)d_in[8];
    const float* be1 = (const float*)d_in[9];
    const float* m1  = (const float*)d_in[10];
    const float* v1  = (const float*)d_in[11];
    const float* g2  = (const float*)d_in[12];
    const float* be2 = (const float*)d_in[13];
    const float* m2  = (const float*)d_in[14];
    const float* v2  = (const float*)d_in[15];
    float* out = (float*)d_out;

    const int* srcp = ei;
    const int* dstp = ei + NE;

    // workspace layout
    float* dinv = (float*)d_ws;                          // NN
    float* A    = dinv + NN;                             // NN*64 f32 activations
    unsigned short* Bh = (unsigned short*)(A + (size_t)NN * 64);  // NN*64 bf16 hs
    int* row_start  = (int*)(Bh + (size_t)NN * 64);      // NN+1
    int* bkcnt      = row_start + NN + 2;                // 512
    int* bb0        = bkcnt + 512;                       // 512
    int* bcur       = bb0 + 512;                         // 512
    int* sorted_src = bcur + 512;                        // NE
    unsigned int* bucketed = (unsigned int*)(sorted_src + NE);  // NE

    dim3 blk(256);
    int gBIN  = (NE + 4095) / 4096;  // 391
    int gG1   = (NN + 63) / 64;      // 1563
    int gG3   = (NN + 127) / 128;    // 782
    int gA    = NN / 4;              // 25000 (1 row per wave, 4 waves/block)

    // CSR build (two-phase radix by dst; per-node hist fused into fine scatter)
    init_small<<<1, 512, 0, stream>>>(bkcnt, bcur);
    bucket_count<<<gBIN, blk, 0, stream>>>(dstp, bkcnt);
    scan2<<<1, 512, 0, stream>>>(bkcnt, bb0);
    bin_kernel<<<gBIN, blk, 0, stream>>>(srcp, dstp, bb0, bcur, bucketed);
    fine_scatter_fused<<<NBUCK, blk, 0, stream>>>(bucketed, bb0, row_start, dinv, sorted_src);

    // layer 1
    gemm_128_64_v3<<<gG1, blk, 0, stream>>>(x, W1, dinv, Bh);
    csr_agg64_v2<<<gA, blk, 0, stream>>>(row_start, sorted_src, Bh, dinv,
                                         b1, g1, be1, m1, v1, A);
    // layer 2
    gemm_64_64_v3<<<gG1, blk, 0, stream>>>(A, W2, dinv, Bh);
    csr_agg64_v2<<<gA, blk, 0, stream>>>(row_start, sorted_src, Bh, dinv,
                                         b2, g2, be2, m2, v2, A);
    // layer 3
    gemm_64_16_v3<<<gG3, blk, 0, stream>>>(A, W3, dinv, Bh);
    csr_agg16_v2<<<gA, blk, 0, stream>>>(row_start, sorted_src, Bh, dinv, b3, out);
}